// Round 4
// baseline (117.977 us; speedup 1.0000x reference)
//
#include <hip/hip_runtime.h>

// TensorProduct: out[z, o*U+u] = sum_{p: idx_out[p]==o} coeffs[p] * x0[z, idx0[p]*U+u] * x1[z, idx1[p]*U+u]
// Z=16384, U=128, NSEG=(32,8,32), P=128, all f32.
// Round 3 (114 us) was LDS+VALU issue-bound in the term loop on top of an ~80-90 us
// memory floor (hbm_bytes 436 MB, L3-assisted). Round 4:
//  - setup kernel sorts terms once into d_ws (kills 8192x per-block sort)
//  - meta + segment bounds via readfirstlane-uniform scalar loads (s_load, off LDS pipe)
//  - staging via global_load_lds width=16 (no ds_write, no VGPR round-trip)

#define Z_DIM 16384
#define U_DIM 128
#define NSEG0 32
#define NSEG1 8
#define NSEG2 32
#define P_DIM 128
#define ZPB   2
#define BLK   512

// ---------- setup: group the P terms by output segment, publish to ws ----------
__global__ __launch_bounds__(128) void tp_setup(
    const float* __restrict__ coeffs,
    const int* __restrict__ idx0,
    const int* __restrict__ idx1,
    const int* __restrict__ idx_out,
    int* __restrict__ off_g,     // [NSEG2+1]
    int2* __restrict__ meta_g)   // [P_DIM]: (i0 | i1<<16, coeff bits), grouped by o
{
    __shared__ int s_cnt[NSEG2];
    __shared__ int s_off[NSEG2 + 1];
    const int t = threadIdx.x;   // exactly P_DIM threads
    if (t < NSEG2) s_cnt[t] = 0;
    __syncthreads();
    const int o = idx_out[t];
    const int r = atomicAdd(&s_cnt[o], 1);
    __syncthreads();
    if (t == 0) {
        int sum = 0;
        for (int i = 0; i < NSEG2; ++i) { s_off[i] = sum; sum += s_cnt[i]; }
        s_off[NSEG2] = sum;
    }
    __syncthreads();
    meta_g[s_off[o] + r] = make_int2(idx0[t] | (idx1[t] << 16), __float_as_int(coeffs[t]));
    if (t <= NSEG2) off_g[t] = s_off[t];
}

// ---------- main ----------
__global__ __launch_bounds__(BLK) void tp_kernel(
    const float* __restrict__ x0,
    const float* __restrict__ x1,
    const int* __restrict__ off_g,
    const int2* __restrict__ meta_g,
    float* __restrict__ out)
{
    __shared__ float s_x0[ZPB][NSEG0 * U_DIM];   // 32 KB
    __shared__ float s_x1[ZPB][NSEG1 * U_DIM];   //  8 KB

    const int t = threadIdx.x;
    const size_t z0 = (size_t)blockIdx.x * ZPB;

    // --- stage x0/x1 rows: async global->LDS, linear layout, 16B/lane ---
    {
        const float4* g0 = reinterpret_cast<const float4*>(x0 + z0 * (NSEG0 * U_DIM));
        const float4* g1 = reinterpret_cast<const float4*>(x1 + z0 * (NSEG1 * U_DIM));
        float4* l0 = reinterpret_cast<float4*>(&s_x0[0][0]);
        float4* l1 = reinterpret_cast<float4*>(&s_x1[0][0]);
#if __has_builtin(__builtin_amdgcn_global_load_lds)
        #pragma unroll
        for (int i = 0; i < (ZPB * NSEG0 * U_DIM / 4) / BLK; ++i)   // 4 iters
            __builtin_amdgcn_global_load_lds(
                (const __attribute__((address_space(1))) void*)(g0 + i * BLK + t),
                (__attribute__((address_space(3))) void*)(l0 + i * BLK + t),
                16, 0, 0);
        __builtin_amdgcn_global_load_lds(
            (const __attribute__((address_space(1))) void*)(g1 + t),
            (__attribute__((address_space(3))) void*)(l1 + t),
            16, 0, 0);
#else
        #pragma unroll
        for (int i = 0; i < (ZPB * NSEG0 * U_DIM / 4) / BLK; ++i)
            l0[i * BLK + t] = g0[i * BLK + t];
        l1[t] = g1[t];
#endif
    }
    __syncthreads();   // drains vmcnt before any LDS read

    // --- compute: wave = 4 segments; lanes = (zl in [0,2), uq in [0,32)) ---
    const int w4 = __builtin_amdgcn_readfirstlane(t >> 6) * 4;  // SGPR segment base
    const int zl = (t >> 5) & 1;
    const int uq = t & 31;

    const float* x0base = &s_x0[zl][uq * 4];
    const float* x1base = &s_x1[zl][uq * 4];
    const size_t z = z0 + zl;
    float4* orow = reinterpret_cast<float4*>(out + z * (NSEG2 * U_DIM)) + uq;

    #pragma unroll
    for (int oo = 0; oo < 4; ++oo) {
        const int o = w4 + oo;
        const int b = off_g[o];          // uniform -> s_load
        const int e = off_g[o + 1];
        float4 acc = make_float4(0.f, 0.f, 0.f, 0.f);
        for (int k = b; k < e; ++k) {
            const int2  m = meta_g[k];   // uniform -> s_load_dwordx2 (scalar cache)
            const float c = __int_as_float(m.y);
            const float4 a = *reinterpret_cast<const float4*>(x0base + (m.x & 0xffff) * U_DIM);
            const float4 v = *reinterpret_cast<const float4*>(x1base + (m.x >> 16)    * U_DIM);
            acc.x = fmaf(c, a.x * v.x, acc.x);
            acc.y = fmaf(c, a.y * v.y, acc.y);
            acc.z = fmaf(c, a.z * v.z, acc.z);
            acc.w = fmaf(c, a.w * v.w, acc.w);
        }
        orow[o * (U_DIM / 4)] = acc;     // coalesced dwordx4 store
    }
}

extern "C" void kernel_launch(void* const* d_in, const int* in_sizes, int n_in,
                              void* d_out, int out_size, void* d_ws, size_t ws_size,
                              hipStream_t stream) {
    const float* x0      = (const float*)d_in[0];
    const float* x1      = (const float*)d_in[1];
    const float* coeffs  = (const float*)d_in[2];
    const int*   idx0    = (const int*)d_in[3];
    const int*   idx1    = (const int*)d_in[4];
    const int*   idx_out = (const int*)d_in[5];
    float* out = (float*)d_out;

    int*  off_g  = (int*)d_ws;                         // 33 ints
    int2* meta_g = (int2*)((char*)d_ws + 256);         // 128 int2, 8B-aligned

    tp_setup<<<1, P_DIM, 0, stream>>>(coeffs, idx0, idx1, idx_out, off_g, meta_g);
    tp_kernel<<<Z_DIM / ZPB, BLK, 0, stream>>>(x0, x1, off_g, meta_g, out);
}